// Round 7
// baseline (580.718 us; speedup 1.0000x reference)
//
#include <hip/hip_runtime.h>
#include <hip/hip_bf16.h>
#include <cstdint>

#define CDIV(a,b) (((a)+(b)-1)/(b))

__device__ __forceinline__ float lrelu(float x){ return x > 0.f ? x : 0.2f*x; }
__device__ __forceinline__ float eluf(float x){ return x > 0.f ? x : __expf(x) - 1.f; }
__device__ __forceinline__ unsigned short f2bf(float f){          // RNE float->bf16
  unsigned x = __float_as_uint(f);
  return (unsigned short)((x + 0x7fffu + ((x >> 16) & 1u)) >> 16);
}
__device__ __forceinline__ float bf2f(unsigned short u){ return __uint_as_float(((unsigned)u) << 16); }

// ---------------- CSR build (by dst) ----------------
__global__ void hist_k(const int* __restrict__ ei, int* __restrict__ deg, int ne, int etot){
  int e = blockIdx.x*256 + threadIdx.x;
  if (e >= etot) return;
  int d = (e < ne) ? ei[ne + e] : (e - ne);
  atomicAdd(&deg[d], 1);
}

constexpr int SCHUNK = 2048;

__global__ __launch_bounds__(256) void scan_part_k(const int* __restrict__ in, int* __restrict__ out,
                                                   int* __restrict__ blksum, int n){
  __shared__ int lds[256];
  int base = blockIdx.x*SCHUNK + threadIdx.x*8;
  int v[8]; int tsum = 0;
  #pragma unroll
  for (int k=0;k<8;k++){ int idx=base+k; int x=(idx<n)?in[idx]:0; v[k]=tsum; tsum+=x; }
  lds[threadIdx.x]=tsum; __syncthreads();
  for (int off=1; off<256; off<<=1){
    int y = (threadIdx.x>= (unsigned)off)? lds[threadIdx.x-off]:0;
    __syncthreads();
    lds[threadIdx.x]+=y;
    __syncthreads();
  }
  int excl = lds[threadIdx.x] - tsum;
  #pragma unroll
  for (int k=0;k<8;k++){ int idx=base+k; if(idx<n) out[idx]=excl+v[k]; }
  if (threadIdx.x==255) blksum[blockIdx.x]=lds[255];
}

__global__ __launch_bounds__(256) void scan_top_k(int* __restrict__ blksum, int nb){
  __shared__ int lds[256];
  int x = ((int)threadIdx.x<nb)? blksum[threadIdx.x]:0;
  lds[threadIdx.x]=x; __syncthreads();
  for (int off=1; off<256; off<<=1){
    int y=(threadIdx.x>=(unsigned)off)?lds[threadIdx.x-off]:0;
    __syncthreads();
    lds[threadIdx.x]+=y;
    __syncthreads();
  }
  if ((int)threadIdx.x<nb) blksum[threadIdx.x]=lds[threadIdx.x]-x;
}

__global__ void scan_add_k(int* __restrict__ rowstart, const int* __restrict__ blksum,
                           int* __restrict__ cursor, int n, int etot){
  int i = blockIdx.x*256+threadIdx.x;
  if (i<n){ int r = rowstart[i]+blksum[i/SCHUNK]; rowstart[i]=r; cursor[i]=r; }
  if (i==0) rowstart[n]=etot;
}

// range-split scatter: only edges with dst in [lo,hi) participate
__global__ void scatter_k(const int* __restrict__ ei, int* __restrict__ cursor,
                          int* __restrict__ edge_src, int ne, int etot, int lo, int hi){
  int e = blockIdx.x*256+threadIdx.x;
  if (e>=etot) return;
  int s,d;
  if (e<ne){ s=ei[e]; d=ei[ne+e]; } else { s=e-ne; d=s; }
  if (d < lo || d >= hi) return;
  int p = atomicAdd(&cursor[d],1);
  edge_src[p]=s;
}

// ---------------- register-tiled GEMM + fused attention logits (bf16 H output) ----------------
template<int K, int KC, int M, int NPT, int H>
__global__ __launch_bounds__(256) void gemm_att_k(const float* __restrict__ X, const float* __restrict__ W,
    const float* __restrict__ attS, const float* __restrict__ attD,
    unsigned short* __restrict__ Hb, float* __restrict__ asrc, float* __restrict__ adst, int n){
  constexpr int CG = M/8;
  constexpr int NG = 256/CG;
  constexpr int NT = NG*NPT;
  constexpr int XS = KC + 4;
  __shared__ float Xl[NT*XS];
  __shared__ float Wl[KC*M];

  const int tid = threadIdx.x;
  const int cg  = tid % CG;
  const int nd  = tid / CG;
  const int base = blockIdx.x * NT;

  float acc[NPT][8];
  #pragma unroll
  for (int j=0;j<NPT;++j)
    #pragma unroll
    for (int c=0;c<8;++c) acc[j][c]=0.f;

  for (int kc0 = 0; kc0 < K; kc0 += KC){
    __syncthreads();
    for (int i = tid; i < NT*KC/4; i += 256){
      int node = i / (KC/4);
      int k4   = i % (KC/4);
      float4 v = make_float4(0.f,0.f,0.f,0.f);
      if (base + node < n) v = *(const float4*)&X[(size_t)(base+node)*K + kc0 + k4*4];
      *(float4*)&Xl[node*XS + k4*4] = v;
    }
    const float* Wsrc = W + (size_t)kc0*M;
    for (int i = tid; i < KC*M/4; i += 256)
      *(float4*)&Wl[i*4] = *(const float4*)&Wsrc[i*4];
    __syncthreads();

    #pragma unroll 4
    for (int k4 = 0; k4 < KC/4; ++k4){
      float4 xv[NPT];
      #pragma unroll
      for (int j=0;j<NPT;++j) xv[j] = *(const float4*)&Xl[(nd + NG*j)*XS + k4*4];
      #pragma unroll
      for (int kk=0;kk<4;++kk){
        float4 w0 = *(const float4*)&Wl[(k4*4+kk)*M + cg*8];
        float4 w1 = *(const float4*)&Wl[(k4*4+kk)*M + cg*8 + 4];
        #pragma unroll
        for (int j=0;j<NPT;++j){
          float x = ((const float*)&xv[j])[kk];
          acc[j][0] += x*w0.x; acc[j][1] += x*w0.y; acc[j][2] += x*w0.z; acc[j][3] += x*w0.w;
          acc[j][4] += x*w1.x; acc[j][5] += x*w1.y; acc[j][6] += x*w1.z; acc[j][7] += x*w1.w;
        }
      }
    }
  }

  const int c0 = cg*8;
  float s0=attS[c0],s1=attS[c0+1],s2=attS[c0+2],s3=attS[c0+3],
        s4=attS[c0+4],s5=attS[c0+5],s6=attS[c0+6],s7=attS[c0+7];
  float d0=attD[c0],d1=attD[c0+1],d2=attD[c0+2],d3=attD[c0+3],
        d4=attD[c0+4],d5=attD[c0+5],d6=attD[c0+6],d7=attD[c0+7];
  #pragma unroll
  for (int j=0;j<NPT;++j){
    int node = base + nd + NG*j;
    float vs = acc[j][0]*s0+acc[j][1]*s1+acc[j][2]*s2+acc[j][3]*s3
             + acc[j][4]*s4+acc[j][5]*s5+acc[j][6]*s6+acc[j][7]*s7;
    float vd = acc[j][0]*d0+acc[j][1]*d1+acc[j][2]*d2+acc[j][3]*d3
             + acc[j][4]*d4+acc[j][5]*d5+acc[j][6]*d6+acc[j][7]*d7;
    vs += __shfl_xor(vs,1); vs += __shfl_xor(vs,2);
    vd += __shfl_xor(vd,1); vd += __shfl_xor(vd,2);
    if (node < n){
      uint4 pk;
      pk.x = (unsigned)f2bf(acc[j][0]) | ((unsigned)f2bf(acc[j][1])<<16);
      pk.y = (unsigned)f2bf(acc[j][2]) | ((unsigned)f2bf(acc[j][3])<<16);
      pk.z = (unsigned)f2bf(acc[j][4]) | ((unsigned)f2bf(acc[j][5])<<16);
      pk.w = (unsigned)f2bf(acc[j][6]) | ((unsigned)f2bf(acc[j][7])<<16);
      *(uint4*)&Hb[(size_t)node*M + c0] = pk;
      if ((cg & 3)==0){
        int head = cg>>2;
        asrc[(size_t)node*H+head]=vs;
        adst[(size_t)node*H+head]=vd;
      }
    }
  }
}

// ---------------- H=4 softmax + aggregation + bias + ELU (+residual), one wave per dst ----------------
// Fast path (deg<=64): single-pass logits, normalized alpha staged in LDS;
// phase-3 gather 8 edges in flight (latency-bound phase -> maximize MLP).
template<bool RES>
__global__ __launch_bounds__(256) void agg4_k(const unsigned short* __restrict__ Hb, const float* __restrict__ asrc,
    const float* __restrict__ adst, const int* __restrict__ rowstart, const int* __restrict__ esrc,
    const float* __restrict__ bias, float* __restrict__ out, int n){
  __shared__ float alphaS[4][64][4];
  const int w    = threadIdx.x >> 6;
  const int lane = threadIdx.x & 63;
  int wid  = (int)((blockIdx.x*256 + threadIdx.x) >> 6);
  if (wid >= n) return;
  wid = __builtin_amdgcn_readfirstlane(wid);
  const int rs = rowstart[wid], re = rowstart[wid+1];
  const int deg = re - rs;
  const float4 adv = *(const float4*)&adst[(size_t)wid*4];
  const int head = lane >> 4;

  float acc0 = 0.f, acc1 = 0.f;

  if (deg <= 64){
    // one edge per lane: load src + asrc ONCE, keep in registers
    int s = 0;
    float l0=-1e30f,l1=-1e30f,l2=-1e30f,l3=-1e30f;
    if (lane < deg){
      s = esrc[rs + lane];
      float4 a4 = *(const float4*)&asrc[(size_t)s*4];
      l0 = lrelu(a4.x+adv.x); l1 = lrelu(a4.y+adv.y);
      l2 = lrelu(a4.z+adv.z); l3 = lrelu(a4.w+adv.w);
    }
    float m0=l0,m1=l1,m2=l2,m3=l3;
    #pragma unroll
    for (int mask=32; mask; mask>>=1){
      m0=fmaxf(m0,__shfl_xor(m0,mask)); m1=fmaxf(m1,__shfl_xor(m1,mask));
      m2=fmaxf(m2,__shfl_xor(m2,mask)); m3=fmaxf(m3,__shfl_xor(m3,mask));
    }
    float e0=__expf(l0-m0), e1=__expf(l1-m1), e2=__expf(l2-m2), e3=__expf(l3-m3);
    float s0=e0,s1=e1,s2=e2,s3=e3;
    #pragma unroll
    for (int mask=32; mask; mask>>=1){
      s0+=__shfl_xor(s0,mask); s1+=__shfl_xor(s1,mask);
      s2+=__shfl_xor(s2,mask); s3+=__shfl_xor(s3,mask);
    }
    // normalized alpha to LDS (invalid lanes write 0)
    *(float4*)&alphaS[w][lane][0] = make_float4(e0/s0, e1/s1, e2/s2, e3/s3);

    int jj = 0;
    // 8 edges in flight
    for (; jj+8 <= deg; jj += 8){
      int sj0 = __builtin_amdgcn_readlane(s, jj+0);
      int sj1 = __builtin_amdgcn_readlane(s, jj+1);
      int sj2 = __builtin_amdgcn_readlane(s, jj+2);
      int sj3 = __builtin_amdgcn_readlane(s, jj+3);
      int sj4 = __builtin_amdgcn_readlane(s, jj+4);
      int sj5 = __builtin_amdgcn_readlane(s, jj+5);
      int sj6 = __builtin_amdgcn_readlane(s, jj+6);
      int sj7 = __builtin_amdgcn_readlane(s, jj+7);
      ushort2 h0 = ((const ushort2*)(Hb + (size_t)sj0*128))[lane];
      ushort2 h1 = ((const ushort2*)(Hb + (size_t)sj1*128))[lane];
      ushort2 h2 = ((const ushort2*)(Hb + (size_t)sj2*128))[lane];
      ushort2 h3 = ((const ushort2*)(Hb + (size_t)sj3*128))[lane];
      ushort2 h4 = ((const ushort2*)(Hb + (size_t)sj4*128))[lane];
      ushort2 h5 = ((const ushort2*)(Hb + (size_t)sj5*128))[lane];
      ushort2 h6 = ((const ushort2*)(Hb + (size_t)sj6*128))[lane];
      ushort2 h7 = ((const ushort2*)(Hb + (size_t)sj7*128))[lane];
      float a0 = alphaS[w][jj+0][head];
      float a1 = alphaS[w][jj+1][head];
      float a2 = alphaS[w][jj+2][head];
      float a3 = alphaS[w][jj+3][head];
      float a4 = alphaS[w][jj+4][head];
      float a5 = alphaS[w][jj+5][head];
      float a6 = alphaS[w][jj+6][head];
      float a7 = alphaS[w][jj+7][head];
      acc0 += a0*bf2f(h0.x) + a1*bf2f(h1.x) + a2*bf2f(h2.x) + a3*bf2f(h3.x)
            + a4*bf2f(h4.x) + a5*bf2f(h5.x) + a6*bf2f(h6.x) + a7*bf2f(h7.x);
      acc1 += a0*bf2f(h0.y) + a1*bf2f(h1.y) + a2*bf2f(h2.y) + a3*bf2f(h3.y)
            + a4*bf2f(h4.y) + a5*bf2f(h5.y) + a6*bf2f(h6.y) + a7*bf2f(h7.y);
    }
    for (; jj+4 <= deg; jj += 4){
      int sj0 = __builtin_amdgcn_readlane(s, jj+0);
      int sj1 = __builtin_amdgcn_readlane(s, jj+1);
      int sj2 = __builtin_amdgcn_readlane(s, jj+2);
      int sj3 = __builtin_amdgcn_readlane(s, jj+3);
      ushort2 h0 = ((const ushort2*)(Hb + (size_t)sj0*128))[lane];
      ushort2 h1 = ((const ushort2*)(Hb + (size_t)sj1*128))[lane];
      ushort2 h2 = ((const ushort2*)(Hb + (size_t)sj2*128))[lane];
      ushort2 h3 = ((const ushort2*)(Hb + (size_t)sj3*128))[lane];
      float a0 = alphaS[w][jj+0][head];
      float a1 = alphaS[w][jj+1][head];
      float a2 = alphaS[w][jj+2][head];
      float a3 = alphaS[w][jj+3][head];
      acc0 += a0*bf2f(h0.x) + a1*bf2f(h1.x) + a2*bf2f(h2.x) + a3*bf2f(h3.x);
      acc1 += a0*bf2f(h0.y) + a1*bf2f(h1.y) + a2*bf2f(h2.y) + a3*bf2f(h3.y);
    }
    for (; jj < deg; ++jj){
      int sj = __builtin_amdgcn_readlane(s, jj);
      ushort2 hv = ((const ushort2*)(Hb + (size_t)sj*128))[lane];
      float a = alphaS[w][jj][head];
      acc0 += a*bf2f(hv.x);
      acc1 += a*bf2f(hv.y);
    }
  } else {
    // ---- slow path (deg>64): three-phase ----
    float adl[4] = {adv.x, adv.y, adv.z, adv.w};
    float m[4] = {-1e30f,-1e30f,-1e30f,-1e30f};
    for (int i = rs + lane; i < re; i += 64){
      int s = esrc[i];
      float4 a4 = *(const float4*)&asrc[(size_t)s*4];
      m[0]=fmaxf(m[0], lrelu(a4.x+adl[0]));
      m[1]=fmaxf(m[1], lrelu(a4.y+adl[1]));
      m[2]=fmaxf(m[2], lrelu(a4.z+adl[2]));
      m[3]=fmaxf(m[3], lrelu(a4.w+adl[3]));
    }
    #pragma unroll
    for (int h=0; h<4; ++h){
      #pragma unroll
      for (int mask=32; mask; mask>>=1) m[h] = fmaxf(m[h], __shfl_xor(m[h], mask));
    }
    float sum[4] = {0.f,0.f,0.f,0.f};
    for (int i = rs + lane; i < re; i += 64){
      int s = esrc[i];
      float4 a4 = *(const float4*)&asrc[(size_t)s*4];
      sum[0]+=__expf(lrelu(a4.x+adl[0])-m[0]);
      sum[1]+=__expf(lrelu(a4.y+adl[1])-m[1]);
      sum[2]+=__expf(lrelu(a4.z+adl[2])-m[2]);
      sum[3]+=__expf(lrelu(a4.w+adl[3])-m[3]);
    }
    #pragma unroll
    for (int h=0; h<4; ++h){
      #pragma unroll
      for (int mask=32; mask; mask>>=1) sum[h]+=__shfl_xor(sum[h],mask);
    }
    const float ad = adl[head], mm = m[head], iv = 1.f/sum[head];
    int i = rs;
    for (; i+4 <= re; i += 4){
      int s0=esrc[i], s1=esrc[i+1], s2=esrc[i+2], s3=esrc[i+3];
      float a0 = asrc[(size_t)s0*4+head];
      float a1 = asrc[(size_t)s1*4+head];
      float a2 = asrc[(size_t)s2*4+head];
      float a3 = asrc[(size_t)s3*4+head];
      ushort2 h0 = ((const ushort2*)(Hb + (size_t)s0*128))[lane];
      ushort2 h1 = ((const ushort2*)(Hb + (size_t)s1*128))[lane];
      ushort2 h2 = ((const ushort2*)(Hb + (size_t)s2*128))[lane];
      ushort2 h3 = ((const ushort2*)(Hb + (size_t)s3*128))[lane];
      float e0=__expf(lrelu(a0+ad)-mm)*iv;
      float e1=__expf(lrelu(a1+ad)-mm)*iv;
      float e2=__expf(lrelu(a2+ad)-mm)*iv;
      float e3=__expf(lrelu(a3+ad)-mm)*iv;
      acc0 += e0*bf2f(h0.x) + e1*bf2f(h1.x) + e2*bf2f(h2.x) + e3*bf2f(h3.x);
      acc1 += e0*bf2f(h0.y) + e1*bf2f(h1.y) + e2*bf2f(h2.y) + e3*bf2f(h3.y);
    }
    for (; i < re; ++i){
      int s = esrc[i];
      float a = asrc[(size_t)s*4+head];
      ushort2 hv = ((const ushort2*)(Hb + (size_t)s*128))[lane];
      float e = __expf(lrelu(a+ad)-mm)*iv;
      acc0 += e*bf2f(hv.x);
      acc1 += e*bf2f(hv.y);
    }
  }

  float2 bv = *(const float2*)&bias[2*lane];
  float v0 = eluf(acc0 + bv.x);
  float v1 = eluf(acc1 + bv.y);
  if (RES){
    float2 rv = *(const float2*)&out[(size_t)wid*128 + 2*lane];
    v0 += rv.x; v1 += rv.y;
  }
  *(float2*)&out[(size_t)wid*128 + 2*lane] = make_float2(v0, v1);
}

// ---------------- H=1 softmax + aggregation + bias + ELU + reg/cls heads ----------------
__global__ __launch_bounds__(256) void agg1_heads_k(const unsigned short* __restrict__ Hb, const float* __restrict__ asrc,
    const float* __restrict__ adst, const int* __restrict__ rowstart, const int* __restrict__ esrc,
    const float* __restrict__ bias,
    const float* __restrict__ rw, const float* __restrict__ rb,
    const float* __restrict__ cw, const float* __restrict__ cb,
    float* __restrict__ out, int n){
  __shared__ float alphaS[4][64];
  const int w    = threadIdx.x >> 6;
  const int lane = threadIdx.x & 63;
  int wid  = (int)((blockIdx.x*256 + threadIdx.x) >> 6);
  if (wid >= n) return;
  wid = __builtin_amdgcn_readfirstlane(wid);
  const int rs = rowstart[wid], re = rowstart[wid+1];
  const int deg = re - rs;
  const float adl = adst[wid];
  const int q = lane >> 4, c2 = lane & 15;

  float acc0 = 0.f, acc1 = 0.f;

  if (deg <= 64){
    int s = 0;
    float l = -1e30f;
    if (lane < deg){
      s = esrc[rs + lane];
      l = lrelu(asrc[s]+adl);
    }
    float m = l;
    #pragma unroll
    for (int mask=32; mask; mask>>=1) m = fmaxf(m, __shfl_xor(m, mask));
    float e = __expf(l-m);
    float sum = e;
    #pragma unroll
    for (int mask=32; mask; mask>>=1) sum += __shfl_xor(sum, mask);
    alphaS[w][lane] = e/sum;          // invalid lanes -> 0

    for (int jj = 0; jj < deg; jj += 4){
      int idx = jj + q;
      int sj = __shfl(s, idx);
      float av = (idx < 64) ? alphaS[w][idx] : 0.f;
      ushort2 hv = ((const ushort2*)(Hb + (size_t)sj*32))[c2];
      acc0 += av*bf2f(hv.x);
      acc1 += av*bf2f(hv.y);
    }
  } else {
    float m = -1e30f;
    for (int i = rs + lane; i < re; i += 64) m = fmaxf(m, lrelu(asrc[esrc[i]]+adl));
    #pragma unroll
    for (int mask=32; mask; mask>>=1) m = fmaxf(m, __shfl_xor(m, mask));
    float sum = 0.f;
    for (int i = rs + lane; i < re; i += 64) sum += __expf(lrelu(asrc[esrc[i]]+adl)-m);
    #pragma unroll
    for (int mask=32; mask; mask>>=1) sum += __shfl_xor(sum, mask);
    const float iv = 1.f/sum;
    for (int i = rs; i < re; i += 4){
      int eidx = i + q;
      if (eidx < re){
        int s = esrc[eidx];
        float a = asrc[s];
        float e = __expf(lrelu(a+adl)-m)*iv;
        ushort2 hv = ((const ushort2*)(Hb + (size_t)s*32))[c2];
        acc0 += e*bf2f(hv.x);
        acc1 += e*bf2f(hv.y);
      }
    }
  }

  acc0 += __shfl_xor(acc0,16); acc0 += __shfl_xor(acc0,32);
  acc1 += __shfl_xor(acc1,16); acc1 += __shfl_xor(acc1,32);

  float2 bv = *(const float2*)&bias[2*c2];
  float v0 = eluf(acc0 + bv.x);
  float v1 = eluf(acc1 + bv.y);
  float r  = v0*rw[2*c2] + v1*rw[2*c2+1];
  float cl = v0*cw[2*c2] + v1*cw[2*c2+1];
  #pragma unroll
  for (int mask=1; mask<16; mask<<=1){ r += __shfl_xor(r, mask); cl += __shfl_xor(cl, mask); }
  if (lane == 0){
    out[wid]     = r  + rb[0];
    out[n + wid] = cl + cb[0];
  }
}

extern "C" void kernel_launch(void* const* d_in, const int* in_sizes, int n_in,
                              void* d_out, int out_size, void* d_ws, size_t ws_size,
                              hipStream_t stream){
  const float* x   = (const float*)d_in[0];
  const int*   ei  = (const int*)d_in[1];
  const float* W1  = (const float*)d_in[2];
  const float* aS1 = (const float*)d_in[3];
  const float* aD1 = (const float*)d_in[4];
  const float* b1  = (const float*)d_in[5];
  const float* W2  = (const float*)d_in[6];
  const float* aS2 = (const float*)d_in[7];
  const float* aD2 = (const float*)d_in[8];
  const float* b2  = (const float*)d_in[9];
  const float* W3  = (const float*)d_in[10];
  const float* aS3 = (const float*)d_in[11];
  const float* aD3 = (const float*)d_in[12];
  const float* b3  = (const float*)d_in[13];
  const float* rw  = (const float*)d_in[14];
  const float* rb  = (const float*)d_in[15];
  const float* cw  = (const float*)d_in[16];
  const float* cb  = (const float*)d_in[17];
  float* out = (float*)d_out;

  const int n    = in_sizes[0] / 16;   // 100000
  const int ne   = in_sizes[1] / 2;    // 1600000
  const int etot = ne + n;             // + self loops

  // workspace layout
  float* A    = (float*)d_ws;                 // [n,128] layer input / residual (fp32)
  float* Bf   = A  + (size_t)n*128;           // [n,128] bf16 h slot
  unsigned short* Hb = (unsigned short*)Bf;
  float* asrc = Bf + (size_t)n*128;           // [n,4]
  float* adst = asrc + (size_t)n*4;           // [n,4]
  int* deg    = (int*)(adst + (size_t)n*4);
  int* rowst  = deg + n;                      // [n+1]
  int* cursor = rowst + n + 1;                // [n]
  int* esrc   = cursor + n;                   // [etot]
  int* blksum = esrc + etot;                  // [64]

  // ---- CSR build ----
  hipMemsetAsync(deg, 0, (size_t)n*sizeof(int), stream);
  hist_k<<<CDIV(etot,256),256,0,stream>>>(ei, deg, ne, etot);
  int nblk = CDIV(n, SCHUNK);
  scan_part_k<<<nblk,256,0,stream>>>(deg, rowst, blksum, n);
  scan_top_k<<<1,256,0,stream>>>(blksum, nblk);
  scan_add_k<<<CDIV(n,256),256,0,stream>>>(rowst, blksum, cursor, n, etot);
  for (int p = 0; p < 4; ++p){
    int lo = (int)((size_t)n * p / 4);
    int hi = (int)((size_t)n * (p+1) / 4);
    scatter_k<<<CDIV(etot,256),256,0,stream>>>(ei, cursor, esrc, ne, etot, lo, hi);
  }

  // ---- layer 1 ----  (K=16, M=128, NPT=4 -> NT=64)
  gemm_att_k<16,16,128,4,4><<<CDIV(n,64),256,0,stream>>>(x, W1, aS1, aD1, Hb, asrc, adst, n);
  agg4_k<false><<<CDIV(n,4),256,0,stream>>>(Hb, asrc, adst, rowst, esrc, b1, A, n);

  // ---- layer 2 (+residual) ----  (K=128, KC=32, M=128, NPT=4 -> NT=64)
  gemm_att_k<128,32,128,4,4><<<CDIV(n,64),256,0,stream>>>(A, W2, aS2, aD2, Hb, asrc, adst, n);
  agg4_k<true><<<CDIV(n,4),256,0,stream>>>(Hb, asrc, adst, rowst, esrc, b2, A, n);

  // ---- layer 3 (K=128, M=32, NPT=1 -> NT=64) + heads fused ----
  gemm_att_k<128,32,32,1,1><<<CDIV(n,64),256,0,stream>>>(A, W3, aS3, aD3, Hb, asrc, adst, n);
  agg1_heads_k<<<CDIV(n,4),256,0,stream>>>(Hb, asrc, adst, rowst, esrc, b3, rw, rb, cw, cb, out, n);
}

// Round 8
// 579.373 us; speedup vs baseline: 1.0023x; 1.0023x over previous
//
#include <hip/hip_runtime.h>
#include <hip/hip_bf16.h>
#include <cstdint>

#define CDIV(a,b) (((a)+(b)-1)/(b))

__device__ __forceinline__ float lrelu(float x){ return x > 0.f ? x : 0.2f*x; }
__device__ __forceinline__ float eluf(float x){ return x > 0.f ? x : __expf(x) - 1.f; }
__device__ __forceinline__ unsigned short f2bf(float f){          // RNE float->bf16
  unsigned x = __float_as_uint(f);
  return (unsigned short)((x + 0x7fffu + ((x >> 16) & 1u)) >> 16);
}
__device__ __forceinline__ float bf2f(unsigned short u){ return __uint_as_float(((unsigned)u) << 16); }

// ---------------- CSR build (by dst) ----------------
__global__ void hist_k(const int* __restrict__ ei, int* __restrict__ deg, int ne, int etot){
  int e = blockIdx.x*256 + threadIdx.x;
  if (e >= etot) return;
  int d = (e < ne) ? ei[ne + e] : (e - ne);
  atomicAdd(&deg[d], 1);
}

constexpr int SCHUNK = 2048;

__global__ __launch_bounds__(256) void scan_part_k(const int* __restrict__ in, int* __restrict__ out,
                                                   int* __restrict__ blksum, int n){
  __shared__ int lds[256];
  int base = blockIdx.x*SCHUNK + threadIdx.x*8;
  int v[8]; int tsum = 0;
  #pragma unroll
  for (int k=0;k<8;k++){ int idx=base+k; int x=(idx<n)?in[idx]:0; v[k]=tsum; tsum+=x; }
  lds[threadIdx.x]=tsum; __syncthreads();
  for (int off=1; off<256; off<<=1){
    int y = (threadIdx.x>= (unsigned)off)? lds[threadIdx.x-off]:0;
    __syncthreads();
    lds[threadIdx.x]+=y;
    __syncthreads();
  }
  int excl = lds[threadIdx.x] - tsum;
  #pragma unroll
  for (int k=0;k<8;k++){ int idx=base+k; if(idx<n) out[idx]=excl+v[k]; }
  if (threadIdx.x==255) blksum[blockIdx.x]=lds[255];
}

__global__ __launch_bounds__(256) void scan_top_k(int* __restrict__ blksum, int nb){
  __shared__ int lds[256];
  int x = ((int)threadIdx.x<nb)? blksum[threadIdx.x]:0;
  lds[threadIdx.x]=x; __syncthreads();
  for (int off=1; off<256; off<<=1){
    int y=(threadIdx.x>=(unsigned)off)?lds[threadIdx.x-off]:0;
    __syncthreads();
    lds[threadIdx.x]+=y;
    __syncthreads();
  }
  if ((int)threadIdx.x<nb) blksum[threadIdx.x]=lds[threadIdx.x]-x;
}

__global__ void scan_add_k(int* __restrict__ rowstart, const int* __restrict__ blksum,
                           int* __restrict__ cursor, int n, int etot){
  int i = blockIdx.x*256+threadIdx.x;
  if (i<n){ int r = rowstart[i]+blksum[i/SCHUNK]; rowstart[i]=r; cursor[i]=r; }
  if (i==0) rowstart[n]=etot;
}

// range-split scatter: only edges with dst in [lo,hi) participate
__global__ void scatter_k(const int* __restrict__ ei, int* __restrict__ cursor,
                          int* __restrict__ edge_src, int ne, int etot, int lo, int hi){
  int e = blockIdx.x*256+threadIdx.x;
  if (e>=etot) return;
  int s,d;
  if (e<ne){ s=ei[e]; d=ei[ne+e]; } else { s=e-ne; d=s; }
  if (d < lo || d >= hi) return;
  int p = atomicAdd(&cursor[d],1);
  edge_src[p]=s;
}

// ---------------- register-tiled GEMM + fused attention logits (bf16 H output) ----------------
template<int K, int KC, int M, int NPT, int H>
__global__ __launch_bounds__(256) void gemm_att_k(const float* __restrict__ X, const float* __restrict__ W,
    const float* __restrict__ attS, const float* __restrict__ attD,
    unsigned short* __restrict__ Hb, float* __restrict__ asrc, float* __restrict__ adst, int n){
  constexpr int CG = M/8;
  constexpr int NG = 256/CG;
  constexpr int NT = NG*NPT;
  constexpr int XS = KC + 4;
  __shared__ float Xl[NT*XS];
  __shared__ float Wl[KC*M];

  const int tid = threadIdx.x;
  const int cg  = tid % CG;
  const int nd  = tid / CG;
  const int base = blockIdx.x * NT;

  float acc[NPT][8];
  #pragma unroll
  for (int j=0;j<NPT;++j)
    #pragma unroll
    for (int c=0;c<8;++c) acc[j][c]=0.f;

  for (int kc0 = 0; kc0 < K; kc0 += KC){
    __syncthreads();
    for (int i = tid; i < NT*KC/4; i += 256){
      int node = i / (KC/4);
      int k4   = i % (KC/4);
      float4 v = make_float4(0.f,0.f,0.f,0.f);
      if (base + node < n) v = *(const float4*)&X[(size_t)(base+node)*K + kc0 + k4*4];
      *(float4*)&Xl[node*XS + k4*4] = v;
    }
    const float* Wsrc = W + (size_t)kc0*M;
    for (int i = tid; i < KC*M/4; i += 256)
      *(float4*)&Wl[i*4] = *(const float4*)&Wsrc[i*4];
    __syncthreads();

    #pragma unroll 4
    for (int k4 = 0; k4 < KC/4; ++k4){
      float4 xv[NPT];
      #pragma unroll
      for (int j=0;j<NPT;++j) xv[j] = *(const float4*)&Xl[(nd + NG*j)*XS + k4*4];
      #pragma unroll
      for (int kk=0;kk<4;++kk){
        float4 w0 = *(const float4*)&Wl[(k4*4+kk)*M + cg*8];
        float4 w1 = *(const float4*)&Wl[(k4*4+kk)*M + cg*8 + 4];
        #pragma unroll
        for (int j=0;j<NPT;++j){
          float x = ((const float*)&xv[j])[kk];
          acc[j][0] += x*w0.x; acc[j][1] += x*w0.y; acc[j][2] += x*w0.z; acc[j][3] += x*w0.w;
          acc[j][4] += x*w1.x; acc[j][5] += x*w1.y; acc[j][6] += x*w1.z; acc[j][7] += x*w1.w;
        }
      }
    }
  }

  const int c0 = cg*8;
  float s0=attS[c0],s1=attS[c0+1],s2=attS[c0+2],s3=attS[c0+3],
        s4=attS[c0+4],s5=attS[c0+5],s6=attS[c0+6],s7=attS[c0+7];
  float d0=attD[c0],d1=attD[c0+1],d2=attD[c0+2],d3=attD[c0+3],
        d4=attD[c0+4],d5=attD[c0+5],d6=attD[c0+6],d7=attD[c0+7];
  #pragma unroll
  for (int j=0;j<NPT;++j){
    int node = base + nd + NG*j;
    float vs = acc[j][0]*s0+acc[j][1]*s1+acc[j][2]*s2+acc[j][3]*s3
             + acc[j][4]*s4+acc[j][5]*s5+acc[j][6]*s6+acc[j][7]*s7;
    float vd = acc[j][0]*d0+acc[j][1]*d1+acc[j][2]*d2+acc[j][3]*d3
             + acc[j][4]*d4+acc[j][5]*d5+acc[j][6]*d6+acc[j][7]*d7;
    vs += __shfl_xor(vs,1); vs += __shfl_xor(vs,2);
    vd += __shfl_xor(vd,1); vd += __shfl_xor(vd,2);
    if (node < n){
      uint4 pk;
      pk.x = (unsigned)f2bf(acc[j][0]) | ((unsigned)f2bf(acc[j][1])<<16);
      pk.y = (unsigned)f2bf(acc[j][2]) | ((unsigned)f2bf(acc[j][3])<<16);
      pk.z = (unsigned)f2bf(acc[j][4]) | ((unsigned)f2bf(acc[j][5])<<16);
      pk.w = (unsigned)f2bf(acc[j][6]) | ((unsigned)f2bf(acc[j][7])<<16);
      *(uint4*)&Hb[(size_t)node*M + c0] = pk;
      if ((cg & 3)==0){
        int head = cg>>2;
        asrc[(size_t)node*H+head]=vs;
        adst[(size_t)node*H+head]=vd;
      }
    }
  }
}

// ---------------- H=4 softmax + aggregation + bias + ELU (+residual), one wave per dst ----------------
// Fast path (deg<=64): single-pass logits, normalized alpha staged in LDS.
// __launch_bounds__(256,4): cap occupancy at 4 waves/EU so the allocator has
// VGPRs to keep the 8-edge gather genuinely in flight (round-7: 24 VGPRs
// silently serialized the unroll).
template<bool RES>
__global__ __launch_bounds__(256, 4) void agg4_k(const unsigned short* __restrict__ Hb, const float* __restrict__ asrc,
    const float* __restrict__ adst, const int* __restrict__ rowstart, const int* __restrict__ esrc,
    const float* __restrict__ bias, float* __restrict__ out, int n){
  __shared__ float alphaS[4][64][4];
  const int w    = threadIdx.x >> 6;
  const int lane = threadIdx.x & 63;
  int wid  = (int)((blockIdx.x*256 + threadIdx.x) >> 6);
  if (wid >= n) return;
  wid = __builtin_amdgcn_readfirstlane(wid);
  const int rs = rowstart[wid], re = rowstart[wid+1];
  const int deg = re - rs;
  const float4 adv = *(const float4*)&adst[(size_t)wid*4];
  const int head = lane >> 4;

  float acc0 = 0.f, acc1 = 0.f;

  if (deg <= 64){
    // one edge per lane: load src + asrc ONCE, keep in registers
    int s = 0;
    float l0=-1e30f,l1=-1e30f,l2=-1e30f,l3=-1e30f;
    if (lane < deg){
      s = esrc[rs + lane];
      float4 a4 = *(const float4*)&asrc[(size_t)s*4];
      l0 = lrelu(a4.x+adv.x); l1 = lrelu(a4.y+adv.y);
      l2 = lrelu(a4.z+adv.z); l3 = lrelu(a4.w+adv.w);
    }
    float m0=l0,m1=l1,m2=l2,m3=l3;
    #pragma unroll
    for (int mask=32; mask; mask>>=1){
      m0=fmaxf(m0,__shfl_xor(m0,mask)); m1=fmaxf(m1,__shfl_xor(m1,mask));
      m2=fmaxf(m2,__shfl_xor(m2,mask)); m3=fmaxf(m3,__shfl_xor(m3,mask));
    }
    float e0=__expf(l0-m0), e1=__expf(l1-m1), e2=__expf(l2-m2), e3=__expf(l3-m3);
    float s0=e0,s1=e1,s2=e2,s3=e3;
    #pragma unroll
    for (int mask=32; mask; mask>>=1){
      s0+=__shfl_xor(s0,mask); s1+=__shfl_xor(s1,mask);
      s2+=__shfl_xor(s2,mask); s3+=__shfl_xor(s3,mask);
    }
    // normalized alpha to LDS (invalid lanes write 0)
    *(float4*)&alphaS[w][lane][0] = make_float4(e0/s0, e1/s1, e2/s2, e3/s3);

    int jj = 0;
    // 8 edges in flight
    for (; jj+8 <= deg; jj += 8){
      int sj0 = __builtin_amdgcn_readlane(s, jj+0);
      int sj1 = __builtin_amdgcn_readlane(s, jj+1);
      int sj2 = __builtin_amdgcn_readlane(s, jj+2);
      int sj3 = __builtin_amdgcn_readlane(s, jj+3);
      int sj4 = __builtin_amdgcn_readlane(s, jj+4);
      int sj5 = __builtin_amdgcn_readlane(s, jj+5);
      int sj6 = __builtin_amdgcn_readlane(s, jj+6);
      int sj7 = __builtin_amdgcn_readlane(s, jj+7);
      ushort2 h0 = ((const ushort2*)(Hb + (size_t)sj0*128))[lane];
      ushort2 h1 = ((const ushort2*)(Hb + (size_t)sj1*128))[lane];
      ushort2 h2 = ((const ushort2*)(Hb + (size_t)sj2*128))[lane];
      ushort2 h3 = ((const ushort2*)(Hb + (size_t)sj3*128))[lane];
      ushort2 h4 = ((const ushort2*)(Hb + (size_t)sj4*128))[lane];
      ushort2 h5 = ((const ushort2*)(Hb + (size_t)sj5*128))[lane];
      ushort2 h6 = ((const ushort2*)(Hb + (size_t)sj6*128))[lane];
      ushort2 h7 = ((const ushort2*)(Hb + (size_t)sj7*128))[lane];
      float a0 = alphaS[w][jj+0][head];
      float a1 = alphaS[w][jj+1][head];
      float a2 = alphaS[w][jj+2][head];
      float a3 = alphaS[w][jj+3][head];
      float a4 = alphaS[w][jj+4][head];
      float a5 = alphaS[w][jj+5][head];
      float a6 = alphaS[w][jj+6][head];
      float a7 = alphaS[w][jj+7][head];
      acc0 += a0*bf2f(h0.x) + a1*bf2f(h1.x) + a2*bf2f(h2.x) + a3*bf2f(h3.x)
            + a4*bf2f(h4.x) + a5*bf2f(h5.x) + a6*bf2f(h6.x) + a7*bf2f(h7.x);
      acc1 += a0*bf2f(h0.y) + a1*bf2f(h1.y) + a2*bf2f(h2.y) + a3*bf2f(h3.y)
            + a4*bf2f(h4.y) + a5*bf2f(h5.y) + a6*bf2f(h6.y) + a7*bf2f(h7.y);
    }
    for (; jj+4 <= deg; jj += 4){
      int sj0 = __builtin_amdgcn_readlane(s, jj+0);
      int sj1 = __builtin_amdgcn_readlane(s, jj+1);
      int sj2 = __builtin_amdgcn_readlane(s, jj+2);
      int sj3 = __builtin_amdgcn_readlane(s, jj+3);
      ushort2 h0 = ((const ushort2*)(Hb + (size_t)sj0*128))[lane];
      ushort2 h1 = ((const ushort2*)(Hb + (size_t)sj1*128))[lane];
      ushort2 h2 = ((const ushort2*)(Hb + (size_t)sj2*128))[lane];
      ushort2 h3 = ((const ushort2*)(Hb + (size_t)sj3*128))[lane];
      float a0 = alphaS[w][jj+0][head];
      float a1 = alphaS[w][jj+1][head];
      float a2 = alphaS[w][jj+2][head];
      float a3 = alphaS[w][jj+3][head];
      acc0 += a0*bf2f(h0.x) + a1*bf2f(h1.x) + a2*bf2f(h2.x) + a3*bf2f(h3.x);
      acc1 += a0*bf2f(h0.y) + a1*bf2f(h1.y) + a2*bf2f(h2.y) + a3*bf2f(h3.y);
    }
    for (; jj < deg; ++jj){
      int sj = __builtin_amdgcn_readlane(s, jj);
      ushort2 hv = ((const ushort2*)(Hb + (size_t)sj*128))[lane];
      float a = alphaS[w][jj][head];
      acc0 += a*bf2f(hv.x);
      acc1 += a*bf2f(hv.y);
    }
  } else {
    // ---- slow path (deg>64): three-phase ----
    float adl[4] = {adv.x, adv.y, adv.z, adv.w};
    float m[4] = {-1e30f,-1e30f,-1e30f,-1e30f};
    for (int i = rs + lane; i < re; i += 64){
      int s = esrc[i];
      float4 a4 = *(const float4*)&asrc[(size_t)s*4];
      m[0]=fmaxf(m[0], lrelu(a4.x+adl[0]));
      m[1]=fmaxf(m[1], lrelu(a4.y+adl[1]));
      m[2]=fmaxf(m[2], lrelu(a4.z+adl[2]));
      m[3]=fmaxf(m[3], lrelu(a4.w+adl[3]));
    }
    #pragma unroll
    for (int h=0; h<4; ++h){
      #pragma unroll
      for (int mask=32; mask; mask>>=1) m[h] = fmaxf(m[h], __shfl_xor(m[h], mask));
    }
    float sum[4] = {0.f,0.f,0.f,0.f};
    for (int i = rs + lane; i < re; i += 64){
      int s = esrc[i];
      float4 a4 = *(const float4*)&asrc[(size_t)s*4];
      sum[0]+=__expf(lrelu(a4.x+adl[0])-m[0]);
      sum[1]+=__expf(lrelu(a4.y+adl[1])-m[1]);
      sum[2]+=__expf(lrelu(a4.z+adl[2])-m[2]);
      sum[3]+=__expf(lrelu(a4.w+adl[3])-m[3]);
    }
    #pragma unroll
    for (int h=0; h<4; ++h){
      #pragma unroll
      for (int mask=32; mask; mask>>=1) sum[h]+=__shfl_xor(sum[h],mask);
    }
    const float ad = adl[head], mm = m[head], iv = 1.f/sum[head];
    int i = rs;
    for (; i+4 <= re; i += 4){
      int s0=esrc[i], s1=esrc[i+1], s2=esrc[i+2], s3=esrc[i+3];
      float a0 = asrc[(size_t)s0*4+head];
      float a1 = asrc[(size_t)s1*4+head];
      float a2 = asrc[(size_t)s2*4+head];
      float a3 = asrc[(size_t)s3*4+head];
      ushort2 h0 = ((const ushort2*)(Hb + (size_t)s0*128))[lane];
      ushort2 h1 = ((const ushort2*)(Hb + (size_t)s1*128))[lane];
      ushort2 h2 = ((const ushort2*)(Hb + (size_t)s2*128))[lane];
      ushort2 h3 = ((const ushort2*)(Hb + (size_t)s3*128))[lane];
      float e0=__expf(lrelu(a0+ad)-mm)*iv;
      float e1=__expf(lrelu(a1+ad)-mm)*iv;
      float e2=__expf(lrelu(a2+ad)-mm)*iv;
      float e3=__expf(lrelu(a3+ad)-mm)*iv;
      acc0 += e0*bf2f(h0.x) + e1*bf2f(h1.x) + e2*bf2f(h2.x) + e3*bf2f(h3.x);
      acc1 += e0*bf2f(h0.y) + e1*bf2f(h1.y) + e2*bf2f(h2.y) + e3*bf2f(h3.y);
    }
    for (; i < re; ++i){
      int s = esrc[i];
      float a = asrc[(size_t)s*4+head];
      ushort2 hv = ((const ushort2*)(Hb + (size_t)s*128))[lane];
      float e = __expf(lrelu(a+ad)-mm)*iv;
      acc0 += e*bf2f(hv.x);
      acc1 += e*bf2f(hv.y);
    }
  }

  float2 bv = *(const float2*)&bias[2*lane];
  float v0 = eluf(acc0 + bv.x);
  float v1 = eluf(acc1 + bv.y);
  if (RES){
    float2 rv = *(const float2*)&out[(size_t)wid*128 + 2*lane];
    v0 += rv.x; v1 += rv.y;
  }
  *(float2*)&out[(size_t)wid*128 + 2*lane] = make_float2(v0, v1);
}

// ---------------- H=1 softmax + aggregation + bias + ELU + reg/cls heads ----------------
__global__ __launch_bounds__(256) void agg1_heads_k(const unsigned short* __restrict__ Hb, const float* __restrict__ asrc,
    const float* __restrict__ adst, const int* __restrict__ rowstart, const int* __restrict__ esrc,
    const float* __restrict__ bias,
    const float* __restrict__ rw, const float* __restrict__ rb,
    const float* __restrict__ cw, const float* __restrict__ cb,
    float* __restrict__ out, int n){
  __shared__ float alphaS[4][64];
  const int w    = threadIdx.x >> 6;
  const int lane = threadIdx.x & 63;
  int wid  = (int)((blockIdx.x*256 + threadIdx.x) >> 6);
  if (wid >= n) return;
  wid = __builtin_amdgcn_readfirstlane(wid);
  const int rs = rowstart[wid], re = rowstart[wid+1];
  const int deg = re - rs;
  const float adl = adst[wid];
  const int q = lane >> 4, c2 = lane & 15;

  float acc0 = 0.f, acc1 = 0.f;

  if (deg <= 64){
    int s = 0;
    float l = -1e30f;
    if (lane < deg){
      s = esrc[rs + lane];
      l = lrelu(asrc[s]+adl);
    }
    float m = l;
    #pragma unroll
    for (int mask=32; mask; mask>>=1) m = fmaxf(m, __shfl_xor(m, mask));
    float e = __expf(l-m);
    float sum = e;
    #pragma unroll
    for (int mask=32; mask; mask>>=1) sum += __shfl_xor(sum, mask);
    alphaS[w][lane] = e/sum;          // invalid lanes -> 0

    for (int jj = 0; jj < deg; jj += 4){
      int idx = jj + q;
      int sj = __shfl(s, idx);
      float av = (idx < 64) ? alphaS[w][idx] : 0.f;
      ushort2 hv = ((const ushort2*)(Hb + (size_t)sj*32))[c2];
      acc0 += av*bf2f(hv.x);
      acc1 += av*bf2f(hv.y);
    }
  } else {
    float m = -1e30f;
    for (int i = rs + lane; i < re; i += 64) m = fmaxf(m, lrelu(asrc[esrc[i]]+adl));
    #pragma unroll
    for (int mask=32; mask; mask>>=1) m = fmaxf(m, __shfl_xor(m, mask));
    float sum = 0.f;
    for (int i = rs + lane; i < re; i += 64) sum += __expf(lrelu(asrc[esrc[i]]+adl)-m);
    #pragma unroll
    for (int mask=32; mask; mask>>=1) sum += __shfl_xor(sum, mask);
    const float iv = 1.f/sum;
    for (int i = rs; i < re; i += 4){
      int eidx = i + q;
      if (eidx < re){
        int s = esrc[eidx];
        float a = asrc[s];
        float e = __expf(lrelu(a+adl)-m)*iv;
        ushort2 hv = ((const ushort2*)(Hb + (size_t)s*32))[c2];
        acc0 += e*bf2f(hv.x);
        acc1 += e*bf2f(hv.y);
      }
    }
  }

  acc0 += __shfl_xor(acc0,16); acc0 += __shfl_xor(acc0,32);
  acc1 += __shfl_xor(acc1,16); acc1 += __shfl_xor(acc1,32);

  float2 bv = *(const float2*)&bias[2*c2];
  float v0 = eluf(acc0 + bv.x);
  float v1 = eluf(acc1 + bv.y);
  float r  = v0*rw[2*c2] + v1*rw[2*c2+1];
  float cl = v0*cw[2*c2] + v1*cw[2*c2+1];
  #pragma unroll
  for (int mask=1; mask<16; mask<<=1){ r += __shfl_xor(r, mask); cl += __shfl_xor(cl, mask); }
  if (lane == 0){
    out[wid]     = r  + rb[0];
    out[n + wid] = cl + cb[0];
  }
}

extern "C" void kernel_launch(void* const* d_in, const int* in_sizes, int n_in,
                              void* d_out, int out_size, void* d_ws, size_t ws_size,
                              hipStream_t stream){
  const float* x   = (const float*)d_in[0];
  const int*   ei  = (const int*)d_in[1];
  const float* W1  = (const float*)d_in[2];
  const float* aS1 = (const float*)d_in[3];
  const float* aD1 = (const float*)d_in[4];
  const float* b1  = (const float*)d_in[5];
  const float* W2  = (const float*)d_in[6];
  const float* aS2 = (const float*)d_in[7];
  const float* aD2 = (const float*)d_in[8];
  const float* b2  = (const float*)d_in[9];
  const float* W3  = (const float*)d_in[10];
  const float* aS3 = (const float*)d_in[11];
  const float* aD3 = (const float*)d_in[12];
  const float* b3  = (const float*)d_in[13];
  const float* rw  = (const float*)d_in[14];
  const float* rb  = (const float*)d_in[15];
  const float* cw  = (const float*)d_in[16];
  const float* cb  = (const float*)d_in[17];
  float* out = (float*)d_out;

  const int n    = in_sizes[0] / 16;   // 100000
  const int ne   = in_sizes[1] / 2;    // 1600000
  const int etot = ne + n;             // + self loops

  // workspace layout
  float* A    = (float*)d_ws;                 // [n,128] layer input / residual (fp32)
  float* Bf   = A  + (size_t)n*128;           // [n,128] bf16 h slot
  unsigned short* Hb = (unsigned short*)Bf;
  float* asrc = Bf + (size_t)n*128;           // [n,4]
  float* adst = asrc + (size_t)n*4;           // [n,4]
  int* deg    = (int*)(adst + (size_t)n*4);
  int* rowst  = deg + n;                      // [n+1]
  int* cursor = rowst + n + 1;                // [n]
  int* esrc   = cursor + n;                   // [etot]
  int* blksum = esrc + etot;                  // [64]

  // ---- CSR build ----
  hipMemsetAsync(deg, 0, (size_t)n*sizeof(int), stream);
  hist_k<<<CDIV(etot,256),256,0,stream>>>(ei, deg, ne, etot);
  int nblk = CDIV(n, SCHUNK);
  scan_part_k<<<nblk,256,0,stream>>>(deg, rowst, blksum, n);
  scan_top_k<<<1,256,0,stream>>>(blksum, nblk);
  scan_add_k<<<CDIV(n,256),256,0,stream>>>(rowst, blksum, cursor, n, etot);
  for (int p = 0; p < 4; ++p){
    int lo = (int)((size_t)n * p / 4);
    int hi = (int)((size_t)n * (p+1) / 4);
    scatter_k<<<CDIV(etot,256),256,0,stream>>>(ei, cursor, esrc, ne, etot, lo, hi);
  }

  // ---- layer 1 ----  (K=16, M=128, NPT=4 -> NT=64)
  gemm_att_k<16,16,128,4,4><<<CDIV(n,64),256,0,stream>>>(x, W1, aS1, aD1, Hb, asrc, adst, n);
  agg4_k<false><<<CDIV(n,4),256,0,stream>>>(Hb, asrc, adst, rowst, esrc, b1, A, n);

  // ---- layer 2 (+residual) ----  (K=128, KC=32, M=128, NPT=4 -> NT=64)
  gemm_att_k<128,32,128,4,4><<<CDIV(n,64),256,0,stream>>>(A, W2, aS2, aD2, Hb, asrc, adst, n);
  agg4_k<true><<<CDIV(n,4),256,0,stream>>>(Hb, asrc, adst, rowst, esrc, b2, A, n);

  // ---- layer 3 (K=128, M=32, NPT=1 -> NT=64) + heads fused ----
  gemm_att_k<128,32,32,1,1><<<CDIV(n,64),256,0,stream>>>(A, W3, aS3, aD3, Hb, asrc, adst, n);
  agg1_heads_k<<<CDIV(n,4),256,0,stream>>>(Hb, asrc, adst, rowst, esrc, b3, rw, rb, cw, cb, out, n);
}